// Round 1
// baseline (1441.643 us; speedup 1.0000x reference)
//
#include <hip/hip_runtime.h>
#include <hip/hip_bf16.h>

// TreeNet: T=512 nodes, B=256 batch, D=256 dim, BF=2 branching.
// Decomposition:
//   K0  stack simulation (int only) -> child lists / worklists
//   K1  H = inputs @ W_in + b            (parallel GEMM, into memory region)
//   K2a G[t] += tanh(H[leaf_child]) @ W_ch[i]   (parallel gather-GEMM, x2 lists)
//   K2b memory[leaf] = tanh(H[leaf])     (parallel elementwise)
//   K3  sequential per-batch chain over combine->combine edges (W in VGPRs)
//   K4  out[k] = memory[root[k], k]
// NOTE: uses final child values instead of "value at read time"; identical for
// valid shift-reduce sequences (each stack entry is a completed subtree).

constexpr int T = 512, B = 256, D = 256;
constexpr int NSTK = T + 2;  // 514

// ws layout in u32 units
constexpr int WS_CNT  = 0;        // [2] atomic counters for leaf lists
constexpr int WS_ROOT = 16;       // [256]
constexpr int WS_NW   = 272;      // [256]
constexpr int WS_L0   = 1024;     // [131072] leaf-child entries, i=0
constexpr int WS_L1   = WS_L0 + T * B;     // [131072] i=1
constexpr int WS_WORK = WS_L1 + T * B;     // [256*1024] per-k combine worklist

// ---------------- K0: stack simulation ----------------
// grid 8 x block 64 (32 active lanes each); u16 stacks in LDS (32x515x2 = 33KB)
__global__ __launch_bounds__(64) void k_stack(const int* __restrict__ ar,
                                              unsigned* __restrict__ ws) {
  __shared__ unsigned short stk[32][NSTK + 1];
  int lane = threadIdx.x;
  if (lane >= 32) return;
  int k = blockIdx.x * 32 + lane;
  unsigned short* S = stk[lane];
  for (int i = 0; i < NSTK; i++) S[i] = 0;
  int ptr = 1;  // BF-1
  int nw = 0;
  unsigned* work = ws + WS_WORK + k * 1024;
  unsigned* l0 = ws + WS_L0;
  unsigned* l1 = ws + WS_L1;
  for (int t = 0; t < T; t++) {
    int a = ar[t * B + k];
    int ncc = 0;
    unsigned cc[2];
    for (int i = 0; i < 2; i++) {
      if (a > i) {
        int ci = ptr - i;
        ci = ((ci % NSTK) + NSTK) % NSTK;
        int c = (int)S[ci];
        int ca = ar[c * B + k];
        if (ca <= 0) {  // leaf-like child: contribution handled in K2a
          unsigned e = (unsigned)c | ((unsigned)t << 9) | ((unsigned)k << 18);
          unsigned slot = atomicAdd(ws + WS_CNT + i, 1u);
          if (i == 0) l0[slot] = e; else l1[slot] = e;
        } else {        // combine child: sequential edge for K3
          cc[ncc++] = (unsigned)c | ((unsigned)i << 18);
        }
      }
    }
    if (a >= 1) {  // this node is a combine: K3 must finalize (tanh) it
      if (ncc == 0) {
        work[nw++] = (unsigned)t | (1u << 19) | (1u << 20);  // first|last, no child
      } else {
        for (int e = 0; e < ncc; e++) {
          unsigned w = (unsigned)t | ((cc[e] & 511u) << 9) |
                       (((cc[e] >> 18) & 1u) << 18) | (1u << 21);
          if (e == 0) w |= (1u << 19);
          if (e == ncc - 1) w |= (1u << 20);
          work[nw++] = w;
        }
      }
    }
    int aa = a < 0 ? -a : a;
    ptr = ptr - aa + 1;
    if (a != -1) {
      int pi = ((ptr % NSTK) + NSTK) % NSTK;
      S[pi] = (unsigned short)t;
    }
  }
  int pi = ((ptr % NSTK) + NSTK) % NSTK;
  ws[WS_ROOT + k] = (unsigned)S[pi];
  ws[WS_NW + k] = (unsigned)nw;
}

// ---------------- K1: H = X @ W_in + b ----------------
// 64-row x 256-col tile per wg; thread = 8x8 register tile. grid 2048 x 256.
__global__ __launch_bounds__(256) void k_gemm_h(const float* __restrict__ X,
                                                const float* __restrict__ W,
                                                const float* __restrict__ bias,
                                                float* __restrict__ Hm) {
  int row0 = blockIdx.x * 64;
  __shared__ float As[16][65];
  __shared__ float Bs[16][256];
  int tid = threadIdx.x;
  int cq = tid & 31, rg = tid >> 5;
  float acc[8][8];
#pragma unroll
  for (int q = 0; q < 8; q++) {
    float bv = bias[cq + 32 * q];
#pragma unroll
    for (int rr = 0; rr < 8; rr++) acc[rr][q] = bv;
  }
  int sr = tid >> 2;           // staging row 0..63
  int skc = (tid & 3) * 4;     // staging k-offset
  for (int kk = 0; kk < 256; kk += 16) {
    float4 a4 = *(const float4*)&X[(row0 + sr) * 256 + kk + skc];
    As[skc + 0][sr] = a4.x; As[skc + 1][sr] = a4.y;
    As[skc + 2][sr] = a4.z; As[skc + 3][sr] = a4.w;
#pragma unroll
    for (int r = 0; r < 16; r++) Bs[r][tid] = W[(kk + r) * 256 + tid];
    __syncthreads();
#pragma unroll
    for (int kc = 0; kc < 16; kc++) {
      float a[8], bb[8];
#pragma unroll
      for (int rr = 0; rr < 8; rr++) a[rr] = As[kc][rg * 8 + rr];
#pragma unroll
      for (int q = 0; q < 8; q++) bb[q] = Bs[kc][cq + 32 * q];
#pragma unroll
      for (int rr = 0; rr < 8; rr++)
#pragma unroll
        for (int q = 0; q < 8; q++) acc[rr][q] += a[rr] * bb[q];
    }
    __syncthreads();
  }
#pragma unroll
  for (int rr = 0; rr < 8; rr++)
#pragma unroll
    for (int q = 0; q < 8; q++)
      Hm[(row0 + rg * 8 + rr) * 256 + cq + 32 * q] = acc[rr][q];
}

// ---------------- K2a: gather-GEMM of leaf-child contributions ----------------
__global__ __launch_bounds__(256) void k_leafgemm(const float* __restrict__ Hm,
                                                  float* __restrict__ Gm,
                                                  const float* __restrict__ Wch,
                                                  const unsigned* __restrict__ list,
                                                  const unsigned* __restrict__ cntp,
                                                  int which) {
  unsigned cnt = *cntp;
  unsigned tile0 = blockIdx.x * 64;
  if (tile0 >= cnt) return;
  int ne = (int)min(64u, cnt - tile0);
  __shared__ unsigned ent[64];
  __shared__ float As[16][65];
  __shared__ float Bs[16][256];
  int tid = threadIdx.x;
  if (tid < 64) ent[tid] = (tid < ne) ? list[tile0 + tid] : 0u;
  __syncthreads();
  const float* W = Wch + which * (D * D);
  int cq = tid & 31, rg = tid >> 5;
  float acc[8][8];
#pragma unroll
  for (int rr = 0; rr < 8; rr++)
#pragma unroll
    for (int q = 0; q < 8; q++) acc[rr][q] = 0.0f;
  int sr = tid >> 2;
  int skc = (tid & 3) * 4;
  unsigned se = ent[sr];
  int sc = (int)(se & 511u), skb = (int)((se >> 18) & 255u);
  const float* srow = &Hm[((sc << 8) + skb) * 256];
  for (int kk = 0; kk < 256; kk += 16) {
    float4 a4;
    if (sr < ne) a4 = *(const float4*)&srow[kk + skc];
    else { a4.x = a4.y = a4.z = a4.w = 0.0f; }
    As[skc + 0][sr] = tanhf(a4.x); As[skc + 1][sr] = tanhf(a4.y);
    As[skc + 2][sr] = tanhf(a4.z); As[skc + 3][sr] = tanhf(a4.w);
#pragma unroll
    for (int r = 0; r < 16; r++) Bs[r][tid] = W[(kk + r) * 256 + tid];
    __syncthreads();
#pragma unroll
    for (int kc = 0; kc < 16; kc++) {
      float a[8], bb[8];
#pragma unroll
      for (int rr = 0; rr < 8; rr++) a[rr] = As[kc][rg * 8 + rr];
#pragma unroll
      for (int q = 0; q < 8; q++) bb[q] = Bs[kc][cq + 32 * q];
#pragma unroll
      for (int rr = 0; rr < 8; rr++)
#pragma unroll
        for (int q = 0; q < 8; q++) acc[rr][q] += a[rr] * bb[q];
    }
    __syncthreads();
  }
#pragma unroll
  for (int rr = 0; rr < 8; rr++) {
    int e = rg * 8 + rr;
    if (e < ne) {
      unsigned en = ent[e];
      int t = (int)((en >> 9) & 511u), kb = (int)((en >> 18) & 255u);
      float* dst = &Gm[((t << 8) + kb) * 256];
#pragma unroll
      for (int q = 0; q < 8; q++) dst[cq + 32 * q] += acc[rr][q];
    }
  }
}

// ---------------- K2b: tanh leaves in place ----------------
__global__ __launch_bounds__(256) void k_leaftanh(const int* __restrict__ ar,
                                                  float* __restrict__ Mm) {
  int r0 = blockIdx.x * 64;  // row = t*B + k  == flat index into ar
  __shared__ int lar[64];
  int tid = threadIdx.x;
  if (tid < 64) lar[tid] = ar[r0 + tid];
  __syncthreads();
  for (int r = 0; r < 64; r++) {
    if (lar[r] <= 0) {
      float v = Mm[(r0 + r) * 256 + tid];
      Mm[(r0 + r) * 256 + tid] = tanhf(v);
    }
  }
}

// ---------------- K3: sequential combine chain, one wg per batch ----------------
// 512 threads: thread (j = tid&255, h = tid>>8) holds W_ch[1][h*128..+127][j]
// in 128 VGPRs. Fast path: child row == previous output cached in LDS.
__global__ __launch_bounds__(512) void k_seq(float* __restrict__ Mm,
                                             const float* __restrict__ Wch,
                                             const unsigned* __restrict__ ws) {
  int k = blockIdx.x;
  int tid = threadIdx.x;
  int j = tid & 255, h = tid >> 8;
  __shared__ __align__(16) float crow[256];
  __shared__ float partial[256];
  __shared__ int cached;
  if (tid == 0) cached = -1;
  float w[128];
  const float* W1 = Wch + D * D;
#pragma unroll
  for (int p = 0; p < 128; p++) w[p] = W1[(h * 128 + p) * 256 + j];
  int nw = (int)ws[WS_NW + k];
  const unsigned* work = ws + WS_WORK + k * 1024;
  float acc = 0.0f;
  __syncthreads();
  for (int n = 0; n < nw; n++) {
    unsigned e = work[n];
    int t = (int)(e & 511u), c = (int)((e >> 9) & 511u);
    int wi = (int)((e >> 18) & 1u);
    bool first = (e >> 19) & 1u, last = (e >> 20) & 1u, hasc = (e >> 21) & 1u;
    if (first) acc = (h == 0) ? Mm[((t << 8) + k) * 256 + j] : 0.0f;
    if (hasc) {
      if (c != cached) {  // generic path: load child row from global
        __syncthreads();
        if (tid < 256) crow[tid] = Mm[((c << 8) + k) * 256 + tid];
        if (tid == 0) cached = c;
        __syncthreads();
      }
      if (wi == 1) {  // fast path: register-resident W_ch[1]
#pragma unroll
        for (int p = 0; p < 32; p++) {
          float4 c4 = ((const float4*)crow)[h * 32 + p];
          acc += c4.x * w[4 * p] + c4.y * w[4 * p + 1] +
                 c4.z * w[4 * p + 2] + c4.w * w[4 * p + 3];
        }
      } else {  // rare: stream W_ch[0] from L2
        const float* W0 = Wch;
#pragma unroll 8
        for (int p = 0; p < 128; p++)
          acc += crow[h * 128 + p] * W0[(h * 128 + p) * 256 + j];
      }
    }
    if (last) {
      if (h == 1) partial[j] = acc;
      __syncthreads();
      if (h == 0) {
        float v = tanhf(acc + partial[j]);
        Mm[((t << 8) + k) * 256 + j] = v;
        crow[j] = v;
      }
      if (tid == 0) cached = t;
      __syncthreads();
    }
  }
}

// ---------------- K4: gather roots ----------------
__global__ __launch_bounds__(256) void k_root(const float* __restrict__ Mm,
                                              float* __restrict__ out,
                                              const unsigned* __restrict__ ws) {
  int k = blockIdx.x;
  unsigned r = ws[WS_ROOT + k];
  out[k * 256 + threadIdx.x] = Mm[(((int)r << 8) + k) * 256 + threadIdx.x];
}

extern "C" void kernel_launch(void* const* d_in, const int* in_sizes, int n_in,
                              void* d_out, int out_size, void* d_ws, size_t ws_size,
                              hipStream_t stream) {
  const float* X    = (const float*)d_in[0];
  const int*   AR   = (const int*)d_in[1];
  const float* Win  = (const float*)d_in[2];
  const float* Wch  = (const float*)d_in[3];
  const float* bias = (const float*)d_in[4];
  float* out = (float*)d_out;
  float* Mm  = out + B * D;  // memory region of output doubles as H/G scratch
  unsigned* ws = (unsigned*)d_ws;

  hipMemsetAsync(d_ws, 0, 512, stream);  // zero atomic counters
  k_stack<<<8, 64, 0, stream>>>(AR, ws);
  k_gemm_h<<<(T * B) / 64, 256, 0, stream>>>(X, Win, bias, Mm);
  k_leafgemm<<<(T * B) / 64, 256, 0, stream>>>(Mm, Mm, Wch, ws + WS_L0, ws + WS_CNT + 0, 0);
  k_leafgemm<<<(T * B) / 64, 256, 0, stream>>>(Mm, Mm, Wch, ws + WS_L1, ws + WS_CNT + 1, 1);
  k_leaftanh<<<(T * B) / 64, 256, 0, stream>>>(AR, Mm);
  k_seq<<<B, 512, 0, stream>>>(Mm, Wch, ws);
  k_root<<<B, 256, 0, stream>>>(Mm, out, ws);
}

// Round 2
// 1080.570 us; speedup vs baseline: 1.3342x; 1.3342x over previous
//
#include <hip/hip_runtime.h>
#include <hip/hip_bf16.h>

// TreeNet: T=512 nodes, B=256 batch, D=256 dim, BF=2 branching.
// Decomposition:
//   K0  stack simulation (int only) -> child lists / worklists
//       R2: one block per batch k; top-2 stack slots cached in registers
//       (write-through to LDS backing store); ar column staged in LDS;
//       leaf/work lists buffered in LDS, bulk-reserved with ONE atomic each.
//   K1  H = inputs @ W_in + b            (parallel GEMM, into memory region)
//   K2a G[t] += tanh(H[leaf_child]) @ W_ch[i]   (parallel gather-GEMM, x2 lists)
//   K2b memory[leaf] = tanh(H[leaf])     (parallel elementwise)
//   K3  sequential per-batch chain over combine->combine edges (W in VGPRs)
//   K4  out[k] = memory[root[k], k]

constexpr int T = 512, B = 256, D = 256;

// ws layout in u32 units
constexpr int WS_CNT  = 0;        // [2] atomic counters for leaf lists
constexpr int WS_ROOT = 16;       // [256]
constexpr int WS_NW   = 272;      // [256]
constexpr int WS_L0   = 1024;     // [131072] leaf-child entries, i=0
constexpr int WS_L1   = WS_L0 + T * B;     // [131072] i=1
constexpr int WS_WORK = WS_L1 + T * B;     // [256*1024] per-k combine worklist

// ---------------- K0: stack simulation ----------------
// One block per k. Phase 1: stage ar[:,k] into LDS (256 threads).
// Phase 2: thread 0 runs the serial shift-reduce sim with top-2 register cache.
// Phase 3: bulk-reserve + coalesced copy-out of LDS buffers.
__global__ __launch_bounds__(256) void k_stack(const int* __restrict__ ar,
                                               unsigned* __restrict__ ws) {
  __shared__ int ar_l[T];
  __shared__ int S[1024];          // stack ring buffer (mask 1023), write-through
  __shared__ unsigned lbuf0[T];
  __shared__ unsigned lbuf1[T];
  __shared__ unsigned wbuf[1024];
  __shared__ int cnts[4];          // n0, n1, nw, root
  __shared__ unsigned base0, base1;

  int k = blockIdx.x;
  int tid = threadIdx.x;
  // Phase 1: gather ar column k (strided over L2), zero stack backing
  ar_l[tid]       = ar[tid * B + k];
  ar_l[tid + 256] = ar[(tid + 256) * B + k];
  S[tid] = 0; S[tid + 256] = 0; S[tid + 512] = 0; S[tid + 768] = 0;
  __syncthreads();

  if (tid == 0) {
    int ptr = 1;           // BF-1
    int top = 0, next = 0; // register cache of S[ptr], S[ptr-1]
    int n0 = 0, n1 = 0, nw = 0;
    for (int t = 0; t < T; t++) {
      int a = ar_l[t];
      int aa = a < 0 ? -a : a;
      // classify children (only top-2 ever read, BF=2)
      unsigned cc[2]; int ncc = 0;
      if (a > 0) {
        int c0 = top;
        if (ar_l[c0] <= 0)
          lbuf0[n0++] = (unsigned)c0 | ((unsigned)t << 9) | ((unsigned)k << 18);
        else
          cc[ncc++] = (unsigned)c0;                 // child slot 0 -> W_ch[0]
        if (a > 1) {
          int c1 = next;
          if (ar_l[c1] <= 0)
            lbuf1[n1++] = (unsigned)c1 | ((unsigned)t << 9) | ((unsigned)k << 18);
          else
            cc[ncc++] = (unsigned)c1 | (1u << 18);  // child slot 1 -> W_ch[1]
        }
      }
      if (a >= 1) {  // combine node: K3 must finalize (tanh) it
        if (ncc == 0) {
          wbuf[nw++] = (unsigned)t | (1u << 19) | (1u << 20);
        } else {
          for (int e = 0; e < ncc; e++) {
            unsigned w = (unsigned)t | ((cc[e] & 511u) << 9) |
                         (((cc[e] >> 18) & 1u) << 18) | (1u << 21);
            if (e == 0) w |= (1u << 19);
            if (e == ncc - 1) w |= (1u << 20);
            wbuf[nw++] = w;
          }
        }
      }
      int pnew = ptr - aa + 1;
      if (a != -1) {
        S[pnew & 1023] = t;                 // write-through
        if (aa == 0)      { next = top; top = t; }
        else if (aa == 1) { top = t; }
        else              { top = t; next = S[(pnew - 1) & 1023]; } // refill
      }
      ptr = pnew;
    }
    cnts[0] = n0; cnts[1] = n1; cnts[2] = nw;
    cnts[3] = S[ptr & 1023];
    base0 = atomicAdd(ws + WS_CNT + 0, (unsigned)n0);
    base1 = atomicAdd(ws + WS_CNT + 1, (unsigned)n1);
  }
  __syncthreads();
  // Phase 3: coalesced copy-out
  int n0 = cnts[0], n1 = cnts[1], nw = cnts[2];
  for (int i = tid; i < n0; i += 256) ws[WS_L0 + base0 + i] = lbuf0[i];
  for (int i = tid; i < n1; i += 256) ws[WS_L1 + base1 + i] = lbuf1[i];
  for (int i = tid; i < nw; i += 256) ws[WS_WORK + k * 1024 + i] = wbuf[i];
  if (tid == 0) { ws[WS_NW + k] = (unsigned)nw; ws[WS_ROOT + k] = (unsigned)cnts[3]; }
}

// ---------------- K1: H = X @ W_in + b ----------------
// 64-row x 256-col tile per wg; thread = 8x8 register tile. grid 2048 x 256.
__global__ __launch_bounds__(256) void k_gemm_h(const float* __restrict__ X,
                                                const float* __restrict__ W,
                                                const float* __restrict__ bias,
                                                float* __restrict__ Hm) {
  int row0 = blockIdx.x * 64;
  __shared__ float As[16][65];
  __shared__ float Bs[16][256];
  int tid = threadIdx.x;
  int cq = tid & 31, rg = tid >> 5;
  float acc[8][8];
#pragma unroll
  for (int q = 0; q < 8; q++) {
    float bv = bias[cq + 32 * q];
#pragma unroll
    for (int rr = 0; rr < 8; rr++) acc[rr][q] = bv;
  }
  int sr = tid >> 2;           // staging row 0..63
  int skc = (tid & 3) * 4;     // staging k-offset
  for (int kk = 0; kk < 256; kk += 16) {
    float4 a4 = *(const float4*)&X[(row0 + sr) * 256 + kk + skc];
    As[skc + 0][sr] = a4.x; As[skc + 1][sr] = a4.y;
    As[skc + 2][sr] = a4.z; As[skc + 3][sr] = a4.w;
#pragma unroll
    for (int r = 0; r < 16; r++) Bs[r][tid] = W[(kk + r) * 256 + tid];
    __syncthreads();
#pragma unroll
    for (int kc = 0; kc < 16; kc++) {
      float a[8], bb[8];
#pragma unroll
      for (int rr = 0; rr < 8; rr++) a[rr] = As[kc][rg * 8 + rr];
#pragma unroll
      for (int q = 0; q < 8; q++) bb[q] = Bs[kc][cq + 32 * q];
#pragma unroll
      for (int rr = 0; rr < 8; rr++)
#pragma unroll
        for (int q = 0; q < 8; q++) acc[rr][q] += a[rr] * bb[q];
    }
    __syncthreads();
  }
#pragma unroll
  for (int rr = 0; rr < 8; rr++)
#pragma unroll
    for (int q = 0; q < 8; q++)
      Hm[(row0 + rg * 8 + rr) * 256 + cq + 32 * q] = acc[rr][q];
}

// ---------------- K2a: gather-GEMM of leaf-child contributions ----------------
__global__ __launch_bounds__(256) void k_leafgemm(const float* __restrict__ Hm,
                                                  float* __restrict__ Gm,
                                                  const float* __restrict__ Wch,
                                                  const unsigned* __restrict__ list,
                                                  const unsigned* __restrict__ cntp,
                                                  int which) {
  unsigned cnt = *cntp;
  unsigned tile0 = blockIdx.x * 64;
  if (tile0 >= cnt) return;
  int ne = (int)min(64u, cnt - tile0);
  __shared__ unsigned ent[64];
  __shared__ float As[16][65];
  __shared__ float Bs[16][256];
  int tid = threadIdx.x;
  if (tid < 64) ent[tid] = (tid < ne) ? list[tile0 + tid] : 0u;
  __syncthreads();
  const float* W = Wch + which * (D * D);
  int cq = tid & 31, rg = tid >> 5;
  float acc[8][8];
#pragma unroll
  for (int rr = 0; rr < 8; rr++)
#pragma unroll
    for (int q = 0; q < 8; q++) acc[rr][q] = 0.0f;
  int sr = tid >> 2;
  int skc = (tid & 3) * 4;
  unsigned se = ent[sr];
  int sc = (int)(se & 511u), skb = (int)((se >> 18) & 255u);
  const float* srow = &Hm[((sc << 8) + skb) * 256];
  for (int kk = 0; kk < 256; kk += 16) {
    float4 a4;
    if (sr < ne) a4 = *(const float4*)&srow[kk + skc];
    else { a4.x = a4.y = a4.z = a4.w = 0.0f; }
    As[skc + 0][sr] = tanhf(a4.x); As[skc + 1][sr] = tanhf(a4.y);
    As[skc + 2][sr] = tanhf(a4.z); As[skc + 3][sr] = tanhf(a4.w);
#pragma unroll
    for (int r = 0; r < 16; r++) Bs[r][tid] = W[(kk + r) * 256 + tid];
    __syncthreads();
#pragma unroll
    for (int kc = 0; kc < 16; kc++) {
      float a[8], bb[8];
#pragma unroll
      for (int rr = 0; rr < 8; rr++) a[rr] = As[kc][rg * 8 + rr];
#pragma unroll
      for (int q = 0; q < 8; q++) bb[q] = Bs[kc][cq + 32 * q];
#pragma unroll
      for (int rr = 0; rr < 8; rr++)
#pragma unroll
        for (int q = 0; q < 8; q++) acc[rr][q] += a[rr] * bb[q];
    }
    __syncthreads();
  }
#pragma unroll
  for (int rr = 0; rr < 8; rr++) {
    int e = rg * 8 + rr;
    if (e < ne) {
      unsigned en = ent[e];
      int t = (int)((en >> 9) & 511u), kb = (int)((en >> 18) & 255u);
      float* dst = &Gm[((t << 8) + kb) * 256];
#pragma unroll
      for (int q = 0; q < 8; q++) dst[cq + 32 * q] += acc[rr][q];
    }
  }
}

// ---------------- K2b: tanh leaves in place ----------------
__global__ __launch_bounds__(256) void k_leaftanh(const int* __restrict__ ar,
                                                  float* __restrict__ Mm) {
  int r0 = blockIdx.x * 64;  // row = t*B + k  == flat index into ar
  __shared__ int lar[64];
  int tid = threadIdx.x;
  if (tid < 64) lar[tid] = ar[r0 + tid];
  __syncthreads();
  for (int r = 0; r < 64; r++) {
    if (lar[r] <= 0) {
      float v = Mm[(r0 + r) * 256 + tid];
      Mm[(r0 + r) * 256 + tid] = tanhf(v);
    }
  }
}

// ---------------- K3: sequential combine chain, one wg per batch ----------------
// 512 threads: thread (j = tid&255, h = tid>>8) holds W_ch[1][h*128..+127][j]
// in 128 VGPRs. Fast path: child row == previous output cached in LDS.
__global__ __launch_bounds__(512) void k_seq(float* __restrict__ Mm,
                                             const float* __restrict__ Wch,
                                             const unsigned* __restrict__ ws) {
  int k = blockIdx.x;
  int tid = threadIdx.x;
  int j = tid & 255, h = tid >> 8;
  __shared__ __align__(16) float crow[256];
  __shared__ float partial[256];
  __shared__ int cached;
  if (tid == 0) cached = -1;
  float w[128];
  const float* W1 = Wch + D * D;
#pragma unroll
  for (int p = 0; p < 128; p++) w[p] = W1[(h * 128 + p) * 256 + j];
  int nw = (int)ws[WS_NW + k];
  const unsigned* work = ws + WS_WORK + k * 1024;
  float acc = 0.0f;
  __syncthreads();
  for (int n = 0; n < nw; n++) {
    unsigned e = work[n];
    int t = (int)(e & 511u), c = (int)((e >> 9) & 511u);
    int wi = (int)((e >> 18) & 1u);
    bool first = (e >> 19) & 1u, last = (e >> 20) & 1u, hasc = (e >> 21) & 1u;
    if (first) acc = (h == 0) ? Mm[((t << 8) + k) * 256 + j] : 0.0f;
    if (hasc) {
      if (c != cached) {  // generic path: load child row from global
        __syncthreads();
        if (tid < 256) crow[tid] = Mm[((c << 8) + k) * 256 + tid];
        if (tid == 0) cached = c;
        __syncthreads();
      }
      if (wi == 1) {  // fast path: register-resident W_ch[1]
#pragma unroll
        for (int p = 0; p < 32; p++) {
          float4 c4 = ((const float4*)crow)[h * 32 + p];
          acc += c4.x * w[4 * p] + c4.y * w[4 * p + 1] +
                 c4.z * w[4 * p + 2] + c4.w * w[4 * p + 3];
        }
      } else {  // rare: stream W_ch[0] from L2
        const float* W0 = Wch;
#pragma unroll 8
        for (int p = 0; p < 128; p++)
          acc += crow[h * 128 + p] * W0[(h * 128 + p) * 256 + j];
      }
    }
    if (last) {
      if (h == 1) partial[j] = acc;
      __syncthreads();
      if (h == 0) {
        float v = tanhf(acc + partial[j]);
        Mm[((t << 8) + k) * 256 + j] = v;
        crow[j] = v;
      }
      if (tid == 0) cached = t;
      __syncthreads();
    }
  }
}

// ---------------- K4: gather roots ----------------
__global__ __launch_bounds__(256) void k_root(const float* __restrict__ Mm,
                                              float* __restrict__ out,
                                              const unsigned* __restrict__ ws) {
  int k = blockIdx.x;
  unsigned r = ws[WS_ROOT + k];
  out[k * 256 + threadIdx.x] = Mm[(((int)r << 8) + k) * 256 + threadIdx.x];
}

extern "C" void kernel_launch(void* const* d_in, const int* in_sizes, int n_in,
                              void* d_out, int out_size, void* d_ws, size_t ws_size,
                              hipStream_t stream) {
  const float* X    = (const float*)d_in[0];
  const int*   AR   = (const int*)d_in[1];
  const float* Win  = (const float*)d_in[2];
  const float* Wch  = (const float*)d_in[3];
  const float* bias = (const float*)d_in[4];
  float* out = (float*)d_out;
  float* Mm  = out + B * D;  // memory region of output doubles as H/G scratch
  unsigned* ws = (unsigned*)d_ws;

  hipMemsetAsync(d_ws, 0, 512, stream);  // zero atomic counters
  k_stack<<<B, 256, 0, stream>>>(AR, ws);
  k_gemm_h<<<(T * B) / 64, 256, 0, stream>>>(X, Win, bias, Mm);
  k_leafgemm<<<(T * B) / 64, 256, 0, stream>>>(Mm, Mm, Wch, ws + WS_L0, ws + WS_CNT + 0, 0);
  k_leafgemm<<<(T * B) / 64, 256, 0, stream>>>(Mm, Mm, Wch, ws + WS_L1, ws + WS_CNT + 1, 1);
  k_leaftanh<<<(T * B) / 64, 256, 0, stream>>>(AR, Mm);
  k_seq<<<B, 512, 0, stream>>>(Mm, Wch, ws);
  k_root<<<B, 256, 0, stream>>>(Mm, out, ws);
}